// Round 7
// baseline (98.602 us; speedup 1.0000x reference)
//
#include <hip/hip_runtime.h>
#include <hip/hip_fp16.h>

#define F 128
#define NEG_SLOPE 0.2f
#define NB 4          // src slices: 12.8MB fp16 / 4 = 3.2MB per phase (< 4MiB per-XCD L2)

// Fused prep: blocks [0, nlog) -> per-node logits (+fp16 convert of x_src rows);
// blocks [nlog, ...) -> CSR offsets from sorted dst_idx.
__global__ __launch_bounds__(256)
void prep_kernel(const float* __restrict__ x_src, const float* __restrict__ attn_l,
                 float* __restrict__ el, __half2* __restrict__ xh, int n_src,
                 const float* __restrict__ x_dst, const float* __restrict__ attn_r,
                 float* __restrict__ er, int n_dst,
                 const int* __restrict__ dst_idx, int* __restrict__ offs, int E,
                 int nlog) {
    if ((int)blockIdx.x < nlog) {
        int row  = blockIdx.x * 4 + (threadIdx.x >> 6);
        int lane = threadIdx.x & 63;
        if (row < n_src) {
            float2 xv = *reinterpret_cast<const float2*>(&x_src[(size_t)row * F + lane * 2]);
            float2 av = *reinterpret_cast<const float2*>(&attn_l[lane * 2]);
            if (xh) xh[(size_t)row * (F / 2) + lane] = __floats2half2_rn(xv.x, xv.y);
            float s = xv.x * av.x + xv.y * av.y;
            #pragma unroll
            for (int o = 32; o > 0; o >>= 1) s += __shfl_xor(s, o, 64);
            if (lane == 0) el[row] = s;
        } else if (row < n_src + n_dst) {
            int r = row - n_src;
            float2 xv = *reinterpret_cast<const float2*>(&x_dst[(size_t)r * F + lane * 2]);
            float2 av = *reinterpret_cast<const float2*>(&attn_r[lane * 2]);
            float s = xv.x * av.x + xv.y * av.y;
            #pragma unroll
            for (int o = 32; o > 0; o >>= 1) s += __shfl_xor(s, o, 64);
            if (lane == 0) er[r] = s;
        }
    } else {
        int e = ((int)blockIdx.x - nlog) * 256 + threadIdx.x;
        if (e >= E) return;
        int d = dst_idx[e];
        int prev = (e == 0) ? -1 : dst_idx[e - 1];
        for (int v = prev + 1; v <= d; ++v) offs[v] = e;
        if (e == E - 1)
            for (int v = d + 1; v <= n_dst; ++v) offs[v] = E;
    }
}

// Block per dst node: stable partition of the segment's src indices into NB
// src-range slices. Writes reordered src_r and per-(node,slice) offsets boffs.
// Stability via wave ballots + per-wave prefix (deterministic).
__global__ __launch_bounds__(256)
void reorder_kernel(const int* __restrict__ src_idx, const int* __restrict__ offs,
                    int* __restrict__ src_r, int* __restrict__ boffs,
                    int n_dst, int bdiv) {
    int v   = blockIdx.x;
    int tid = threadIdx.x;
    int start = offs[v], end = offs[v + 1];

    __shared__ int cnt[NB];
    __shared__ int base_[NB];
    __shared__ int wtot[4];

    if (tid < NB) cnt[tid] = 0;
    __syncthreads();
    for (int i = start + tid; i < end; i += 256)
        atomicAdd(&cnt[src_idx[i] / bdiv], 1);
    __syncthreads();
    if (tid == 0) {
        int acc = start;
        #pragma unroll
        for (int b = 0; b < NB; ++b) {
            base_[b] = acc;
            boffs[(size_t)v * (NB + 1) + b] = acc;
            acc += cnt[b];
        }
        boffs[(size_t)v * (NB + 1) + NB] = acc;   // == end
    }
    __syncthreads();

    int lane = tid & 63, wid = tid >> 6;
    for (int cbase = start; cbase < end; cbase += 256) {
        int n = end - cbase; if (n > 256) n = 256;
        int s = 0, b = -1;
        if (tid < n) { s = src_idx[cbase + tid]; b = s / bdiv; }
        #pragma unroll
        for (int bb = 0; bb < NB; ++bb) {
            bool flag = (b == bb);
            unsigned long long m = __ballot(flag);
            int rk = __popcll(m & ((1ULL << lane) - 1ULL));
            if (lane == 0) wtot[wid] = __popcll(m);
            __syncthreads();
            int wpre = 0;
            for (int w = 0; w < wid; ++w) wpre += wtot[w];
            if (flag) src_r[base_[bb] + wpre + rk] = s;
            __syncthreads();
            if (tid == 0) base_[bb] += wtot[0] + wtot[1] + wtot[2] + wtot[3];
            __syncthreads();
        }
    }
}

// One 64-lane wave per dst node (4 per block); processes ONLY slice b's edges.
// Accumulates unnormalized into out (fp32 RMW across launches); last launch
// normalizes by the total denominator (carried in den_ws).
template<bool H>
__global__ __launch_bounds__(256)
void agg_kernel(const __half2* __restrict__ xh, const float* __restrict__ x_src,
                const float* __restrict__ el, const float* __restrict__ er,
                const int* __restrict__ src_r, const int* __restrict__ boffs,
                int nbp1, int b, float* __restrict__ out, float* __restrict__ den_ws,
                int n_dst, int first, int last) {
    int v = blockIdx.x * 4 + (threadIdx.x >> 6);
    if (v >= n_dst) return;
    int lane = threadIdx.x & 63;
    int g    = lane >> 4;
    int l16  = lane & 15;

    int s0e = boffs[(size_t)v * nbp1 + b];
    int s1e = boffs[(size_t)v * nbp1 + b + 1];
    float erv = er[v];

    const float4* x4h = reinterpret_cast<const float4*>(xh);     // 16 float4 / row
    const float4* x4f = reinterpret_cast<const float4*>(x_src);  // 32 float4 / row

    float a0[8], a1[8];
    #pragma unroll
    for (int k = 0; k < 8; ++k) { a0[k] = 0.f; a1[k] = 0.f; }
    float d0 = 0.f, d1 = 0.f;

    int count = s1e - s0e;
    int full  = count & ~7;
    for (int it = 0; it < full; it += 8) {
        int e0 = s0e + it + g;
        int e1 = e0 + 4;
        int s0 = src_r[e0];
        int s1 = src_r[e1];
        float l0 = el[s0] + erv, l1 = el[s1] + erv;
        l0 = l0 > 0.f ? l0 : NEG_SLOPE * l0;
        l1 = l1 > 0.f ? l1 : NEG_SLOPE * l1;
        float w0 = __expf(l0), w1 = __expf(l1);
        d0 += w0; d1 += w1;
        if (H) {
            float4 r0 = x4h[(size_t)s0 * (F / 8) + l16];
            float4 r1 = x4h[(size_t)s1 * (F / 8) + l16];
            const __half2* h0 = reinterpret_cast<const __half2*>(&r0);
            const __half2* h1 = reinterpret_cast<const __half2*>(&r1);
            #pragma unroll
            for (int k = 0; k < 4; ++k) {
                float2 f0 = __half22float2(h0[k]);
                float2 f1 = __half22float2(h1[k]);
                a0[2*k]   += w0 * f0.x;  a0[2*k+1] += w0 * f0.y;
                a1[2*k]   += w1 * f1.x;  a1[2*k+1] += w1 * f1.y;
            }
        } else {
            float4 p0 = x4f[(size_t)s0 * (F/4) + l16*2];
            float4 q0 = x4f[(size_t)s0 * (F/4) + l16*2 + 1];
            float4 p1 = x4f[(size_t)s1 * (F/4) + l16*2];
            float4 q1 = x4f[(size_t)s1 * (F/4) + l16*2 + 1];
            a0[0]+=w0*p0.x; a0[1]+=w0*p0.y; a0[2]+=w0*p0.z; a0[3]+=w0*p0.w;
            a0[4]+=w0*q0.x; a0[5]+=w0*q0.y; a0[6]+=w0*q0.z; a0[7]+=w0*q0.w;
            a1[0]+=w1*p1.x; a1[1]+=w1*p1.y; a1[2]+=w1*p1.z; a1[3]+=w1*p1.w;
            a1[4]+=w1*q1.x; a1[5]+=w1*q1.y; a1[6]+=w1*q1.z; a1[7]+=w1*q1.w;
        }
    }
    for (int e = s0e + full + g; e < s1e; e += 4) {
        int s = src_r[e];
        float l = el[s] + erv;
        l = l > 0.f ? l : NEG_SLOPE * l;
        float w = __expf(l);
        d0 += w;
        if (H) {
            float4 r = x4h[(size_t)s * (F / 8) + l16];
            const __half2* h = reinterpret_cast<const __half2*>(&r);
            #pragma unroll
            for (int k = 0; k < 4; ++k) {
                float2 f = __half22float2(h[k]);
                a0[2*k] += w * f.x;  a0[2*k+1] += w * f.y;
            }
        } else {
            float4 p = x4f[(size_t)s * (F/4) + l16*2];
            float4 q = x4f[(size_t)s * (F/4) + l16*2 + 1];
            a0[0]+=w*p.x; a0[1]+=w*p.y; a0[2]+=w*p.z; a0[3]+=w*p.w;
            a0[4]+=w*q.x; a0[5]+=w*q.y; a0[6]+=w*q.z; a0[7]+=w*q.w;
        }
    }
    #pragma unroll
    for (int k = 0; k < 8; ++k) a0[k] += a1[k];
    d0 += d1;

    #pragma unroll
    for (int k = 0; k < 8; ++k) {
        a0[k] += __shfl_xor(a0[k], 16, 64);
        a0[k] += __shfl_xor(a0[k], 32, 64);
    }
    d0 += __shfl_xor(d0, 16, 64);
    d0 += __shfl_xor(d0, 32, 64);

    if (g == 0) {
        float4* po = reinterpret_cast<float4*>(&out[(size_t)v * F + l16 * 8]);
        float4 o0, o1;
        float dprev = 0.f;
        if (first) {
            o0 = make_float4(0.f, 0.f, 0.f, 0.f);
            o1 = o0;
        } else {
            o0 = po[0]; o1 = po[1];
            dprev = den_ws[v];
        }
        o0.x += a0[0]; o0.y += a0[1]; o0.z += a0[2]; o0.w += a0[3];
        o1.x += a0[4]; o1.y += a0[5]; o1.z += a0[6]; o1.w += a0[7];
        float dtot = dprev + d0;
        if (last) {
            float inv = (dtot > 0.f) ? 1.f / dtot : 0.f;
            o0.x *= inv; o0.y *= inv; o0.z *= inv; o0.w *= inv;
            o1.x *= inv; o1.y *= inv; o1.z *= inv; o1.w *= inv;
        } else if (l16 == 0) {
            den_ws[v] = dtot;
        }
        po[0] = o0;
        po[1] = o1;
    }
}

extern "C" void kernel_launch(void* const* d_in, const int* in_sizes, int n_in,
                              void* d_out, int out_size, void* d_ws, size_t ws_size,
                              hipStream_t stream) {
    const float* x_src   = (const float*)d_in[0];
    const float* x_dst   = (const float*)d_in[1];
    const float* attn_l  = (const float*)d_in[2];
    const float* attn_r  = (const float*)d_in[3];
    const int*   src_idx = (const int*)d_in[4];
    const int*   dst_idx = (const int*)d_in[5];

    int n_src = in_sizes[0] / F;   // 50000
    int n_dst = in_sizes[1] / F;   // 10000
    int E     = in_sizes[4];       // 1600000

    float* out  = (float*)d_out;
    float* el   = (float*)d_ws;                 // n_src floats
    float* er   = el + n_src;                   // n_dst floats
    int*   offs = (int*)(er + n_dst);           // n_dst+1 ints
    uintptr_t p = (uintptr_t)(offs + n_dst + 1);
    p = (p + 15) & ~(uintptr_t)15;
    __half2* xh = (__half2*)p;                  // n_src*F halves = 12.8 MB
    uintptr_t q = p + (size_t)n_src * F * sizeof(__half);
    int*   src_r  = (int*)q;                    // E ints = 6.4 MB
    int*   boffs  = src_r + E;                  // n_dst*(NB+1) ints
    float* den_ws = (float*)(boffs + (size_t)n_dst * (NB + 1));  // n_dst floats

    size_t need_fp16 = (p - (uintptr_t)d_ws) + (size_t)n_src * F * sizeof(__half);
    size_t need_full = ((uintptr_t)(den_ws + n_dst)) - (uintptr_t)d_ws;
    bool fp16ok = ws_size >= need_fp16;
    bool fullok = ws_size >= need_full;

    int nlog = (n_src + n_dst + 3) / 4;
    int noff = (E + 255) / 256;
    prep_kernel<<<nlog + noff, 256, 0, stream>>>(
        x_src, attn_l, el, fp16ok ? xh : nullptr, n_src,
        x_dst, attn_r, er, n_dst, dst_idx, offs, E, nlog);

    int agg_blocks = (n_dst + 3) / 4;
    if (fullok && fp16ok) {
        int bdiv = (n_src + NB - 1) / NB;       // src rows per slice
        reorder_kernel<<<n_dst, 256, 0, stream>>>(src_idx, offs, src_r, boffs,
                                                  n_dst, bdiv);
        for (int b = 0; b < NB; ++b) {
            agg_kernel<true><<<agg_blocks, 256, 0, stream>>>(
                xh, nullptr, el, er, src_r, boffs, NB + 1, b, out, den_ws,
                n_dst, b == 0 ? 1 : 0, b == NB - 1 ? 1 : 0);
        }
    } else if (fp16ok) {
        // unbucketed fp16 fallback: boffs := offs (stride 1), single launch
        agg_kernel<true><<<agg_blocks, 256, 0, stream>>>(
            xh, nullptr, el, er, src_idx, offs, 1, 0, out, nullptr, n_dst, 1, 1);
    } else {
        agg_kernel<false><<<agg_blocks, 256, 0, stream>>>(
            nullptr, x_src, el, er, src_idx, offs, 1, 0, out, nullptr, n_dst, 1, 1);
    }
}

// Round 8
// 90.424 us; speedup vs baseline: 1.0904x; 1.0904x over previous
//
#include <hip/hip_runtime.h>
#include <hip/hip_fp16.h>

#define F 128
#define NEG_SLOPE 0.2f
#define NB 8          // src slices: 12.8MB fp16 / 8 = 1.6MB per XCD L2 (4MiB)

// Fused prep: blocks [0, nlog) -> per-node logits (+fp16 convert of x_src rows);
// blocks [nlog, ...) -> CSR offsets from sorted dst_idx.
__global__ __launch_bounds__(256)
void prep_kernel(const float* __restrict__ x_src, const float* __restrict__ attn_l,
                 float* __restrict__ el, __half2* __restrict__ xh, int n_src,
                 const float* __restrict__ x_dst, const float* __restrict__ attn_r,
                 float* __restrict__ er, int n_dst,
                 const int* __restrict__ dst_idx, int* __restrict__ offs, int E,
                 int nlog) {
    if ((int)blockIdx.x < nlog) {
        int row  = blockIdx.x * 4 + (threadIdx.x >> 6);
        int lane = threadIdx.x & 63;
        if (row < n_src) {
            float2 xv = *reinterpret_cast<const float2*>(&x_src[(size_t)row * F + lane * 2]);
            float2 av = *reinterpret_cast<const float2*>(&attn_l[lane * 2]);
            if (xh) xh[(size_t)row * (F / 2) + lane] = __floats2half2_rn(xv.x, xv.y);
            float s = xv.x * av.x + xv.y * av.y;
            #pragma unroll
            for (int o = 32; o > 0; o >>= 1) s += __shfl_xor(s, o, 64);
            if (lane == 0) el[row] = s;
        } else if (row < n_src + n_dst) {
            int r = row - n_src;
            float2 xv = *reinterpret_cast<const float2*>(&x_dst[(size_t)r * F + lane * 2]);
            float2 av = *reinterpret_cast<const float2*>(&attn_r[lane * 2]);
            float s = xv.x * av.x + xv.y * av.y;
            #pragma unroll
            for (int o = 32; o > 0; o >>= 1) s += __shfl_xor(s, o, 64);
            if (lane == 0) er[r] = s;
        }
    } else {
        int e = ((int)blockIdx.x - nlog) * 256 + threadIdx.x;
        if (e >= E) return;
        int d = dst_idx[e];
        int prev = (e == 0) ? -1 : dst_idx[e - 1];
        for (int v = prev + 1; v <= d; ++v) offs[v] = e;
        if (e == E - 1)
            for (int v = d + 1; v <= n_dst; ++v) offs[v] = E;
    }
}

// Block per dst node: stable partition of the segment's src indices into NB
// src-range slices. Writes reordered src_r and per-(node,slice) offsets boffs.
__global__ __launch_bounds__(256)
void reorder_kernel(const int* __restrict__ src_idx, const int* __restrict__ offs,
                    int* __restrict__ src_r, int* __restrict__ boffs,
                    int n_dst, int bdiv) {
    int v   = blockIdx.x;
    int tid = threadIdx.x;
    int start = offs[v], end = offs[v + 1];

    __shared__ int cnt[NB];
    __shared__ int base_[NB];
    __shared__ int wtot[4];

    if (tid < NB) cnt[tid] = 0;
    __syncthreads();
    for (int i = start + tid; i < end; i += 256)
        atomicAdd(&cnt[src_idx[i] / bdiv], 1);
    __syncthreads();
    if (tid == 0) {
        int acc = start;
        #pragma unroll
        for (int b = 0; b < NB; ++b) {
            base_[b] = acc;
            boffs[(size_t)v * (NB + 1) + b] = acc;
            acc += cnt[b];
        }
        boffs[(size_t)v * (NB + 1) + NB] = acc;   // == end
    }
    __syncthreads();

    int lane = tid & 63, wid = tid >> 6;
    for (int cbase = start; cbase < end; cbase += 256) {
        int n = end - cbase; if (n > 256) n = 256;
        int s = 0, b = -1;
        if (tid < n) { s = src_idx[cbase + tid]; b = s / bdiv; }
        #pragma unroll
        for (int bb = 0; bb < NB; ++bb) {
            bool flag = (b == bb);
            unsigned long long m = __ballot(flag);
            int rk = __popcll(m & ((1ULL << lane) - 1ULL));
            if (lane == 0) wtot[wid] = __popcll(m);
            __syncthreads();
            int wpre = 0;
            for (int w = 0; w < wid; ++w) wpre += wtot[w];
            if (flag) src_r[base_[bb] + wpre + rk] = s;
            __syncthreads();
            if (tid == 0) base_[bb] += wtot[0] + wtot[1] + wtot[2] + wtot[3];
            __syncthreads();
        }
    }
}

// SINGLE launch, spatially XCD-phase-locked: slice = blockIdx % NB. Under the
// CP's round-robin block->XCD dispatch, XCD x only ever gathers from slice x
// (1.6MB fp16, L2-resident). One 64-lane wave per (node, slice); writes
// UNNORMALIZED partials to part[b] / pden[b] (no atomics, fully deterministic).
__global__ __launch_bounds__(256)
void agg_slice_kernel(const __half2* __restrict__ xh,
                      const float* __restrict__ el,
                      const float* __restrict__ er,
                      const int* __restrict__ src_r,
                      const int* __restrict__ boffs,
                      float* __restrict__ part, float* __restrict__ pden,
                      int n_dst) {
    int b = blockIdx.x & (NB - 1);
    int v = (blockIdx.x >> 3) * 4 + (threadIdx.x >> 6);
    if (v >= n_dst) return;
    int lane = threadIdx.x & 63;
    int g    = lane >> 4;
    int l16  = lane & 15;

    int s0e = boffs[(size_t)v * (NB + 1) + b];
    int s1e = boffs[(size_t)v * (NB + 1) + b + 1];
    float erv = er[v];

    const float4* x4h = reinterpret_cast<const float4*>(xh);     // 16 float4 / row

    float a0[8], a1[8];
    #pragma unroll
    for (int k = 0; k < 8; ++k) { a0[k] = 0.f; a1[k] = 0.f; }
    float d0 = 0.f, d1 = 0.f;

    int count = s1e - s0e;
    int full  = count & ~7;
    for (int it = 0; it < full; it += 8) {
        int e0 = s0e + it + g;
        int e1 = e0 + 4;
        int s0 = src_r[e0];
        int s1 = src_r[e1];
        float l0 = el[s0] + erv, l1 = el[s1] + erv;
        l0 = l0 > 0.f ? l0 : NEG_SLOPE * l0;
        l1 = l1 > 0.f ? l1 : NEG_SLOPE * l1;
        float w0 = __expf(l0), w1 = __expf(l1);
        d0 += w0; d1 += w1;
        float4 r0 = x4h[(size_t)s0 * (F / 8) + l16];
        float4 r1 = x4h[(size_t)s1 * (F / 8) + l16];
        const __half2* h0 = reinterpret_cast<const __half2*>(&r0);
        const __half2* h1 = reinterpret_cast<const __half2*>(&r1);
        #pragma unroll
        for (int k = 0; k < 4; ++k) {
            float2 f0 = __half22float2(h0[k]);
            float2 f1 = __half22float2(h1[k]);
            a0[2*k]   += w0 * f0.x;  a0[2*k+1] += w0 * f0.y;
            a1[2*k]   += w1 * f1.x;  a1[2*k+1] += w1 * f1.y;
        }
    }
    for (int e = s0e + full + g; e < s1e; e += 4) {
        int s = src_r[e];
        float l = el[s] + erv;
        l = l > 0.f ? l : NEG_SLOPE * l;
        float w = __expf(l);
        d0 += w;
        float4 r = x4h[(size_t)s * (F / 8) + l16];
        const __half2* h = reinterpret_cast<const __half2*>(&r);
        #pragma unroll
        for (int k = 0; k < 4; ++k) {
            float2 f = __half22float2(h[k]);
            a0[2*k] += w * f.x;  a0[2*k+1] += w * f.y;
        }
    }
    #pragma unroll
    for (int k = 0; k < 8; ++k) a0[k] += a1[k];
    d0 += d1;

    #pragma unroll
    for (int k = 0; k < 8; ++k) {
        a0[k] += __shfl_xor(a0[k], 16, 64);
        a0[k] += __shfl_xor(a0[k], 32, 64);
    }
    d0 += __shfl_xor(d0, 16, 64);
    d0 += __shfl_xor(d0, 32, 64);

    if (g == 0) {
        float4* pp = reinterpret_cast<float4*>(&part[((size_t)b * n_dst + v) * F + l16 * 8]);
        pp[0] = make_float4(a0[0], a0[1], a0[2], a0[3]);
        pp[1] = make_float4(a0[4], a0[5], a0[6], a0[7]);
        if (l16 == 0) pden[(size_t)b * n_dst + v] = d0;
    }
}

// Combine: out[v,f] = sum_b part[b][v][f] / sum_b pden[b][v]  (fixed order).
__global__ __launch_bounds__(256)
void combine_kernel(const float* __restrict__ part, const float* __restrict__ pden,
                    float* __restrict__ out, int n_dst) {
    int t = blockIdx.x * 256 + threadIdx.x;
    if (t >= n_dst * F) return;
    int v = t >> 7;          // / F
    float num = 0.f, den = 0.f;
    #pragma unroll
    for (int b = 0; b < NB; ++b) {
        num += part[((size_t)b * n_dst) * F + t];
        den += pden[(size_t)b * n_dst + v];
    }
    out[t] = (den > 0.f) ? num / den : 0.f;
}

// Fallback: single-launch wave-per-node over the full segment (round-5 best).
template<bool H>
__global__ __launch_bounds__(256)
void agg_full_kernel(const __half2* __restrict__ xh, const float* __restrict__ x_src,
                     const float* __restrict__ el, const float* __restrict__ er,
                     const int* __restrict__ src_idx, const int* __restrict__ offs,
                     float* __restrict__ out, int n_dst) {
    int v = blockIdx.x * 4 + (threadIdx.x >> 6);
    if (v >= n_dst) return;
    int lane = threadIdx.x & 63;
    int g    = lane >> 4;
    int l16  = lane & 15;

    int start = offs[v];
    int end   = offs[v + 1];
    int count = end - start;
    float erv = er[v];

    const float4* x4h = reinterpret_cast<const float4*>(xh);
    const float4* x4f = reinterpret_cast<const float4*>(x_src);

    float a0[8], a1[8];
    #pragma unroll
    for (int k = 0; k < 8; ++k) { a0[k] = 0.f; a1[k] = 0.f; }
    float d0 = 0.f, d1 = 0.f;

    int full = count & ~7;
    for (int it = 0; it < full; it += 8) {
        int e0 = start + it + g;
        int e1 = e0 + 4;
        int s0 = src_idx[e0];
        int s1 = src_idx[e1];
        float l0 = el[s0] + erv, l1 = el[s1] + erv;
        l0 = l0 > 0.f ? l0 : NEG_SLOPE * l0;
        l1 = l1 > 0.f ? l1 : NEG_SLOPE * l1;
        float w0 = __expf(l0), w1 = __expf(l1);
        d0 += w0; d1 += w1;
        if (H) {
            float4 r0 = x4h[(size_t)s0 * (F / 8) + l16];
            float4 r1 = x4h[(size_t)s1 * (F / 8) + l16];
            const __half2* h0 = reinterpret_cast<const __half2*>(&r0);
            const __half2* h1 = reinterpret_cast<const __half2*>(&r1);
            #pragma unroll
            for (int k = 0; k < 4; ++k) {
                float2 f0 = __half22float2(h0[k]);
                float2 f1 = __half22float2(h1[k]);
                a0[2*k]   += w0 * f0.x;  a0[2*k+1] += w0 * f0.y;
                a1[2*k]   += w1 * f1.x;  a1[2*k+1] += w1 * f1.y;
            }
        } else {
            float4 p0 = x4f[(size_t)s0 * (F/4) + l16*2];
            float4 q0 = x4f[(size_t)s0 * (F/4) + l16*2 + 1];
            float4 p1 = x4f[(size_t)s1 * (F/4) + l16*2];
            float4 q1 = x4f[(size_t)s1 * (F/4) + l16*2 + 1];
            a0[0]+=w0*p0.x; a0[1]+=w0*p0.y; a0[2]+=w0*p0.z; a0[3]+=w0*p0.w;
            a0[4]+=w0*q0.x; a0[5]+=w0*q0.y; a0[6]+=w0*q0.z; a0[7]+=w0*q0.w;
            a1[0]+=w1*p1.x; a1[1]+=w1*p1.y; a1[2]+=w1*p1.z; a1[3]+=w1*p1.w;
            a1[4]+=w1*q1.x; a1[5]+=w1*q1.y; a1[6]+=w1*q1.z; a1[7]+=w1*q1.w;
        }
    }
    for (int e = start + full + g; e < end; e += 4) {
        int s = src_idx[e];
        float l = el[s] + erv;
        l = l > 0.f ? l : NEG_SLOPE * l;
        float w = __expf(l);
        d0 += w;
        if (H) {
            float4 r = x4h[(size_t)s * (F / 8) + l16];
            const __half2* h = reinterpret_cast<const __half2*>(&r);
            #pragma unroll
            for (int k = 0; k < 4; ++k) {
                float2 f = __half22float2(h[k]);
                a0[2*k] += w * f.x;  a0[2*k+1] += w * f.y;
            }
        } else {
            float4 p = x4f[(size_t)s * (F/4) + l16*2];
            float4 q = x4f[(size_t)s * (F/4) + l16*2 + 1];
            a0[0]+=w*p.x; a0[1]+=w*p.y; a0[2]+=w*p.z; a0[3]+=w*p.w;
            a0[4]+=w*q.x; a0[5]+=w*q.y; a0[6]+=w*q.z; a0[7]+=w*q.w;
        }
    }
    #pragma unroll
    for (int k = 0; k < 8; ++k) a0[k] += a1[k];
    d0 += d1;

    #pragma unroll
    for (int k = 0; k < 8; ++k) {
        a0[k] += __shfl_xor(a0[k], 16, 64);
        a0[k] += __shfl_xor(a0[k], 32, 64);
    }
    d0 += __shfl_xor(d0, 16, 64);
    d0 += __shfl_xor(d0, 32, 64);

    if (g == 0) {
        float inv = (count > 0) ? 1.f / d0 : 0.f;
        float4* dst = reinterpret_cast<float4*>(&out[(size_t)v * F + l16 * 8]);
        dst[0] = make_float4(a0[0]*inv, a0[1]*inv, a0[2]*inv, a0[3]*inv);
        dst[1] = make_float4(a0[4]*inv, a0[5]*inv, a0[6]*inv, a0[7]*inv);
    }
}

extern "C" void kernel_launch(void* const* d_in, const int* in_sizes, int n_in,
                              void* d_out, int out_size, void* d_ws, size_t ws_size,
                              hipStream_t stream) {
    const float* x_src   = (const float*)d_in[0];
    const float* x_dst   = (const float*)d_in[1];
    const float* attn_l  = (const float*)d_in[2];
    const float* attn_r  = (const float*)d_in[3];
    const int*   src_idx = (const int*)d_in[4];
    const int*   dst_idx = (const int*)d_in[5];

    int n_src = in_sizes[0] / F;   // 50000
    int n_dst = in_sizes[1] / F;   // 10000
    int E     = in_sizes[4];       // 1600000

    float* out  = (float*)d_out;
    float* el   = (float*)d_ws;                 // n_src floats
    float* er   = el + n_src;                   // n_dst floats
    int*   offs = (int*)(er + n_dst);           // n_dst+1 ints
    uintptr_t p = (uintptr_t)(offs + n_dst + 1);
    p = (p + 15) & ~(uintptr_t)15;
    __half2* xh = (__half2*)p;                  // n_src*F halves = 12.8 MB
    uintptr_t q = p + (size_t)n_src * F * sizeof(__half);
    int*   src_r = (int*)q;                     // E ints = 6.4 MB
    int*   boffs = src_r + E;                   // n_dst*(NB+1) ints
    uintptr_t r  = (uintptr_t)(boffs + (size_t)n_dst * (NB + 1));
    r = (r + 15) & ~(uintptr_t)15;
    float* part  = (float*)r;                   // NB*n_dst*F floats = 41 MB
    float* pden  = part + (size_t)NB * n_dst * F;  // NB*n_dst floats

    size_t need_fp16 = (p - (uintptr_t)d_ws) + (size_t)n_src * F * sizeof(__half);
    size_t need_full = ((uintptr_t)(pden + (size_t)NB * n_dst)) - (uintptr_t)d_ws;
    bool fp16ok = ws_size >= need_fp16;
    bool fullok = ws_size >= need_full;

    int nlog = (n_src + n_dst + 3) / 4;
    int noff = (E + 255) / 256;
    prep_kernel<<<nlog + noff, 256, 0, stream>>>(
        x_src, attn_l, el, fp16ok ? xh : nullptr, n_src,
        x_dst, attn_r, er, n_dst, dst_idx, offs, E, nlog);

    if (fullok && fp16ok) {
        int bdiv = (n_src + NB - 1) / NB;       // src rows per slice
        reorder_kernel<<<n_dst, 256, 0, stream>>>(src_idx, offs, src_r, boffs,
                                                  n_dst, bdiv);
        int ngrp = (n_dst + 3) / 4;
        agg_slice_kernel<<<ngrp * NB, 256, 0, stream>>>(
            xh, el, er, src_r, boffs, part, pden, n_dst);
        combine_kernel<<<(n_dst * F + 255) / 256, 256, 0, stream>>>(
            part, pden, out, n_dst);
    } else if (fp16ok) {
        agg_full_kernel<true><<<(n_dst + 3) / 4, 256, 0, stream>>>(
            xh, nullptr, el, er, src_idx, offs, out, n_dst);
    } else {
        agg_full_kernel<false><<<(n_dst + 3) / 4, 256, 0, stream>>>(
            nullptr, x_src, el, er, src_idx, offs, out, n_dst);
    }
}

// Round 9
// 72.546 us; speedup vs baseline: 1.3592x; 1.2464x over previous
//
#include <hip/hip_runtime.h>
#include <hip/hip_fp16.h>

#define F 128
#define NEG_SLOPE 0.2f
#define NB 4          // src slices: 12.8MB fp16 / 4 = 3.2MB, fits 4MiB per-XCD L2

// fp32 FMA with packed-fp16 operand (no separate convert): acc += w * h.{lo|hi}
#define FMA_MIX_LO(acc, w, h) \
    asm("v_fma_mix_f32 %0, %1, %2, %0 op_sel:[0,0,0] op_sel_hi:[0,1,0]" \
        : "+v"(acc) : "v"(w), "v"(h))
#define FMA_MIX_HI(acc, w, h) \
    asm("v_fma_mix_f32 %0, %1, %2, %0 op_sel:[0,1,0] op_sel_hi:[0,1,0]" \
        : "+v"(acc) : "v"(w), "v"(h))

// Fused prep: blocks [0, nlog): per-node logits (float4 loads, 2 rows/wave)
// + fp16 convert of x_src. Blocks [nlog, ...): CSR offsets from sorted dst_idx.
__global__ __launch_bounds__(256)
void prep_kernel(const float* __restrict__ x_src, const float* __restrict__ attn_l,
                 float* __restrict__ el, __half2* __restrict__ xh, int n_src,
                 const float* __restrict__ x_dst, const float* __restrict__ attn_r,
                 float* __restrict__ er, int n_dst,
                 const int* __restrict__ dst_idx, int* __restrict__ offs, int E,
                 int nlog) {
    if ((int)blockIdx.x < nlog) {
        int wave = blockIdx.x * 4 + (threadIdx.x >> 6);
        int lane = threadIdx.x & 63;
        int half = lane >> 5;
        int l32  = lane & 31;
        int row  = wave * 2 + half;
        const float* x; const float* attn; float* o; int r; bool is_src;
        if (row < n_src)              { x = x_src; attn = attn_l; o = el; r = row; is_src = true; }
        else if (row < n_src + n_dst) { x = x_dst; attn = attn_r; o = er; r = row - n_src; is_src = false; }
        else return;
        float4 xv = reinterpret_cast<const float4*>(x)[(size_t)r * 32 + l32];
        float4 av = reinterpret_cast<const float4*>(attn)[l32];
        if (xh && is_src) {
            __half2 h0 = __floats2half2_rn(xv.x, xv.y);
            __half2 h1 = __floats2half2_rn(xv.z, xv.w);
            uint2 u;
            u.x = *reinterpret_cast<unsigned int*>(&h0);
            u.y = *reinterpret_cast<unsigned int*>(&h1);
            reinterpret_cast<uint2*>(xh)[(size_t)r * 32 + l32] = u;
        }
        float s = xv.x * av.x + xv.y * av.y + xv.z * av.z + xv.w * av.w;
        #pragma unroll
        for (int o_ = 16; o_ > 0; o_ >>= 1) s += __shfl_xor(s, o_, 64);
        if (l32 == 0) o[r] = s;
    } else {
        int e = ((int)blockIdx.x - nlog) * 256 + threadIdx.x;
        if (e >= E) return;
        int d = dst_idx[e];
        int prev = (e == 0) ? -1 : dst_idx[e - 1];
        for (int v = prev + 1; v <= d; ++v) offs[v] = e;
        if (e == E - 1)
            for (int v = d + 1; v <= n_dst; ++v) offs[v] = E;
    }
}

// One WAVE per dst node (4/block, no barriers): stable partition of the segment
// into NB src-range slices; writes ew[e] = (row_offset_scaled, weight) and
// per-(node,slice) offsets boffs. Wave-local ballots -> deterministic.
__global__ __launch_bounds__(256)
void reorder_kernel(const int* __restrict__ src_idx, const int* __restrict__ offs,
                    const float* __restrict__ el, const float* __restrict__ er,
                    int2* __restrict__ ew, int* __restrict__ boffs,
                    int n_dst, float inv_bdiv) {
    int v = blockIdx.x * 4 + (threadIdx.x >> 6);
    if (v >= n_dst) return;
    int lane = threadIdx.x & 63;
    int start = offs[v], end = offs[v + 1];
    float erv = er[v];
    unsigned long long lt = (1ULL << lane) - 1ULL;

    // pass 1: per-slice counts via wave ballots
    int c0 = 0, c1 = 0, c2 = 0, c3 = 0;
    for (int base = start; base < end; base += 64) {
        int e = base + lane;
        int b = -1;
        if (e < end) {
            int s = src_idx[e];
            b = (int)((float)s * inv_bdiv);
            if (b > NB - 1) b = NB - 1;
        }
        c0 += __popcll(__ballot(b == 0));
        c1 += __popcll(__ballot(b == 1));
        c2 += __popcll(__ballot(b == 2));
        c3 += __popcll(__ballot(b == 3));
    }
    int base0 = start;
    int base1 = base0 + c0;
    int base2 = base1 + c1;
    int base3 = base2 + c2;
    if (lane == 0) {
        boffs[(size_t)v * (NB + 1) + 0] = base0;
        boffs[(size_t)v * (NB + 1) + 1] = base1;
        boffs[(size_t)v * (NB + 1) + 2] = base2;
        boffs[(size_t)v * (NB + 1) + 3] = base3;
        boffs[(size_t)v * (NB + 1) + 4] = base3 + c3;
    }

    // pass 2: stable scatter + weight computation
    for (int base = start; base < end; base += 64) {
        int e = base + lane;
        int b = -1, s = 0;
        float w = 0.f;
        if (e < end) {
            s = src_idx[e];
            b = (int)((float)s * inv_bdiv);
            if (b > NB - 1) b = NB - 1;
            float l = el[s] + erv;
            l = l > 0.f ? l : NEG_SLOPE * l;
            w = __expf(l);
        }
        int2 payload = make_int2(s * (F / 8), __float_as_int(w));
        unsigned long long m;
        m = __ballot(b == 0);
        if (b == 0) ew[base0 + __popcll(m & lt)] = payload;
        base0 += __popcll(m);
        m = __ballot(b == 1);
        if (b == 1) ew[base1 + __popcll(m & lt)] = payload;
        base1 += __popcll(m);
        m = __ballot(b == 2);
        if (b == 2) ew[base2 + __popcll(m & lt)] = payload;
        base2 += __popcll(m);
        m = __ballot(b == 3);
        if (b == 3) ew[base3 + __popcll(m & lt)] = payload;
        base3 += __popcll(m);
    }
}

// Single launch, XCD-phase-locked: slice = blockIdx % NB (CP round-robins
// blocks over 8 XCDs -> XCD x only touches slice x&3, 3.2MB, L2-resident).
// Wave per (node, slice); fp16 rows consumed via v_fma_mix (no cvt chain);
// weights precomputed. Writes unnormalized partials (deterministic).
__global__ __launch_bounds__(256)
void agg_slice_kernel(const __half2* __restrict__ xh,
                      const int2* __restrict__ ew,
                      const int* __restrict__ boffs,
                      float* __restrict__ part, float* __restrict__ pden,
                      int n_dst) {
    int b = blockIdx.x & (NB - 1);
    int v = ((int)blockIdx.x >> 2) * 4 + (threadIdx.x >> 6);
    if (v >= n_dst) return;
    int lane = threadIdx.x & 63;
    int g    = lane >> 4;
    int l16  = lane & 15;

    int s0e = boffs[(size_t)v * (NB + 1) + b];
    int s1e = boffs[(size_t)v * (NB + 1) + b + 1];

    const float4* x4h = reinterpret_cast<const float4*>(xh);   // 16 float4 / row

    float a0[8], a1[8];
    #pragma unroll
    for (int k = 0; k < 8; ++k) { a0[k] = 0.f; a1[k] = 0.f; }
    float d0 = 0.f, d1 = 0.f;

    int count = s1e - s0e;
    int full  = count & ~7;
    for (int it = 0; it < full; it += 8) {
        int2 q0 = ew[s0e + it + g];
        int2 q1 = ew[s0e + it + 4 + g];
        float w0 = __int_as_float(q0.y);
        float w1 = __int_as_float(q1.y);
        d0 += w0; d1 += w1;
        float4 r0 = x4h[q0.x + l16];
        float4 r1 = x4h[q1.x + l16];
        const unsigned int* u0 = reinterpret_cast<const unsigned int*>(&r0);
        const unsigned int* u1 = reinterpret_cast<const unsigned int*>(&r1);
        #pragma unroll
        for (int k = 0; k < 4; ++k) {
            FMA_MIX_LO(a0[2*k],   w0, u0[k]);
            FMA_MIX_HI(a0[2*k+1], w0, u0[k]);
            FMA_MIX_LO(a1[2*k],   w1, u1[k]);
            FMA_MIX_HI(a1[2*k+1], w1, u1[k]);
        }
    }
    for (int e = s0e + full + g; e < s1e; e += 4) {
        int2 q = ew[e];
        float w = __int_as_float(q.y);
        d0 += w;
        float4 r = x4h[q.x + l16];
        const unsigned int* u = reinterpret_cast<const unsigned int*>(&r);
        #pragma unroll
        for (int k = 0; k < 4; ++k) {
            FMA_MIX_LO(a0[2*k],   w, u[k]);
            FMA_MIX_HI(a0[2*k+1], w, u[k]);
        }
    }
    #pragma unroll
    for (int k = 0; k < 8; ++k) a0[k] += a1[k];
    d0 += d1;

    #pragma unroll
    for (int k = 0; k < 8; ++k) {
        a0[k] += __shfl_xor(a0[k], 16, 64);
        a0[k] += __shfl_xor(a0[k], 32, 64);
    }
    d0 += __shfl_xor(d0, 16, 64);
    d0 += __shfl_xor(d0, 32, 64);

    if (g == 0) {
        float4* pp = reinterpret_cast<float4*>(&part[((size_t)b * n_dst + v) * F + l16 * 8]);
        pp[0] = make_float4(a0[0], a0[1], a0[2], a0[3]);
        pp[1] = make_float4(a0[4], a0[5], a0[6], a0[7]);
        if (l16 == 0) pden[(size_t)b * n_dst + v] = d0;
    }
}

// out[v,f] = sum_b part[b][v][f] / sum_b pden[b][v]  (fixed order, float4).
__global__ __launch_bounds__(256)
void combine_kernel(const float* __restrict__ part, const float* __restrict__ pden,
                    float* __restrict__ out, int n_dst) {
    int t = blockIdx.x * 256 + threadIdx.x;   // float4 index
    int total = n_dst * (F / 4);
    if (t >= total) return;
    int v = t >> 5;                            // 32 float4 per row
    const float4* p4 = reinterpret_cast<const float4*>(part);
    float4 n = make_float4(0.f, 0.f, 0.f, 0.f);
    float den = 0.f;
    #pragma unroll
    for (int b = 0; b < NB; ++b) {
        float4 u = p4[(size_t)b * total + t];
        n.x += u.x; n.y += u.y; n.z += u.z; n.w += u.w;
        den += pden[(size_t)b * n_dst + v];
    }
    float inv = (den > 0.f) ? 1.f / den : 0.f;
    reinterpret_cast<float4*>(out)[t] = make_float4(n.x*inv, n.y*inv, n.z*inv, n.w*inv);
}

// Fallback: single-launch wave-per-node over full segment (round-5/8 path).
template<bool H>
__global__ __launch_bounds__(256)
void agg_full_kernel(const __half2* __restrict__ xh, const float* __restrict__ x_src,
                     const float* __restrict__ el, const float* __restrict__ er,
                     const int* __restrict__ src_idx, const int* __restrict__ offs,
                     float* __restrict__ out, int n_dst) {
    int v = blockIdx.x * 4 + (threadIdx.x >> 6);
    if (v >= n_dst) return;
    int lane = threadIdx.x & 63;
    int g    = lane >> 4;
    int l16  = lane & 15;

    int start = offs[v];
    int end   = offs[v + 1];
    int count = end - start;
    float erv = er[v];

    const float4* x4h = reinterpret_cast<const float4*>(xh);
    const float4* x4f = reinterpret_cast<const float4*>(x_src);

    float a0[8];
    #pragma unroll
    for (int k = 0; k < 8; ++k) a0[k] = 0.f;
    float d0 = 0.f;

    for (int e = start + g; e < end; e += 4) {
        int s = src_idx[e];
        float l = el[s] + erv;
        l = l > 0.f ? l : NEG_SLOPE * l;
        float w = __expf(l);
        d0 += w;
        if (H) {
            float4 r = x4h[(size_t)s * (F / 8) + l16];
            const unsigned int* u = reinterpret_cast<const unsigned int*>(&r);
            #pragma unroll
            for (int k = 0; k < 4; ++k) {
                FMA_MIX_LO(a0[2*k],   w, u[k]);
                FMA_MIX_HI(a0[2*k+1], w, u[k]);
            }
        } else {
            float4 p = x4f[(size_t)s * (F/4) + l16*2];
            float4 q = x4f[(size_t)s * (F/4) + l16*2 + 1];
            a0[0]+=w*p.x; a0[1]+=w*p.y; a0[2]+=w*p.z; a0[3]+=w*p.w;
            a0[4]+=w*q.x; a0[5]+=w*q.y; a0[6]+=w*q.z; a0[7]+=w*q.w;
        }
    }
    #pragma unroll
    for (int k = 0; k < 8; ++k) {
        a0[k] += __shfl_xor(a0[k], 16, 64);
        a0[k] += __shfl_xor(a0[k], 32, 64);
    }
    d0 += __shfl_xor(d0, 16, 64);
    d0 += __shfl_xor(d0, 32, 64);

    if (g == 0) {
        float inv = (count > 0) ? 1.f / d0 : 0.f;
        float4* dst = reinterpret_cast<float4*>(&out[(size_t)v * F + l16 * 8]);
        dst[0] = make_float4(a0[0]*inv, a0[1]*inv, a0[2]*inv, a0[3]*inv);
        dst[1] = make_float4(a0[4]*inv, a0[5]*inv, a0[6]*inv, a0[7]*inv);
    }
}

extern "C" void kernel_launch(void* const* d_in, const int* in_sizes, int n_in,
                              void* d_out, int out_size, void* d_ws, size_t ws_size,
                              hipStream_t stream) {
    const float* x_src   = (const float*)d_in[0];
    const float* x_dst   = (const float*)d_in[1];
    const float* attn_l  = (const float*)d_in[2];
    const float* attn_r  = (const float*)d_in[3];
    const int*   src_idx = (const int*)d_in[4];
    const int*   dst_idx = (const int*)d_in[5];

    int n_src = in_sizes[0] / F;   // 50000
    int n_dst = in_sizes[1] / F;   // 10000
    int E     = in_sizes[4];       // 1600000

    float* out  = (float*)d_out;
    float* el   = (float*)d_ws;                 // n_src floats
    float* er   = el + n_src;                   // n_dst floats
    int*   offs = (int*)(er + n_dst);           // n_dst+1 ints
    uintptr_t p = (uintptr_t)(offs + n_dst + 1);
    p = (p + 15) & ~(uintptr_t)15;
    __half2* xh = (__half2*)p;                  // n_src*F halves = 12.8 MB
    uintptr_t q = p + (size_t)n_src * F * sizeof(__half);
    q = (q + 15) & ~(uintptr_t)15;
    int2*  ew    = (int2*)q;                    // E int2 = 12.8 MB
    int*   boffs = (int*)(ew + E);              // n_dst*(NB+1) ints
    uintptr_t r  = (uintptr_t)(boffs + (size_t)n_dst * (NB + 1));
    r = (r + 15) & ~(uintptr_t)15;
    float* part  = (float*)r;                   // NB*n_dst*F floats = 20.5 MB
    float* pden  = part + (size_t)NB * n_dst * F;  // NB*n_dst floats

    size_t need_fp16 = (q - (uintptr_t)d_ws);
    size_t need_full = ((uintptr_t)(pden + (size_t)NB * n_dst)) - (uintptr_t)d_ws;
    bool fp16ok = ws_size >= need_fp16;
    bool fullok = ws_size >= need_full;

    int nlog = (n_src + n_dst + 7) / 8;         // 8 rows per block (4 waves x 2)
    int noff = (E + 255) / 256;
    prep_kernel<<<nlog + noff, 256, 0, stream>>>(
        x_src, attn_l, el, fp16ok ? xh : nullptr, n_src,
        x_dst, attn_r, er, n_dst, dst_idx, offs, E, nlog);

    if (fullok && fp16ok) {
        int bdiv = (n_src + NB - 1) / NB;       // src rows per slice
        float inv_bdiv = 1.0f / (float)bdiv;
        reorder_kernel<<<(n_dst + 3) / 4, 256, 0, stream>>>(
            src_idx, offs, el, er, ew, boffs, n_dst, inv_bdiv);
        int ngrp = (n_dst + 3) / 4;
        agg_slice_kernel<<<ngrp * NB, 256, 0, stream>>>(
            xh, ew, boffs, part, pden, n_dst);
        combine_kernel<<<(n_dst * (F / 4) + 255) / 256, 256, 0, stream>>>(
            part, pden, out, n_dst);
    } else if (fp16ok) {
        agg_full_kernel<true><<<(n_dst + 3) / 4, 256, 0, stream>>>(
            xh, nullptr, el, er, src_idx, offs, out, n_dst);
    } else {
        agg_full_kernel<false><<<(n_dst + 3) / 4, 256, 0, stream>>>(
            nullptr, x_src, el, er, src_idx, offs, out, n_dst);
    }
}